// Round 1
// baseline (234.423 us; speedup 1.0000x reference)
//
#include <hip/hip_runtime.h>
#include <stdint.h>

// Conv2DUF: 3x3 s1 p1 conv, x[32][128][56][56] f32, weight[1152][256] f32
// (k = c*9 + kh*3 + kw), bias[256] f32 -> out[32][256][56][56] f32.
// bf16 implicit GEMM: M = 32*56*56 = 100352, N = 256, K = 1152.
//  ws: xt = bf16 x, GROUPED layout [c8grp(16)][B][58][58][8]  (halo = 0)
//      wt = bf16 weight reordered  [9][256][128]              (K-contiguous)
// R3: conv_gemm -> BK=32, triple-buffered LDS, raw s_barrier + counted
//     s_waitcnt vmcnt(12) (T3+T4); pad_transpose -> LDS-free streaming
//     transpose via grouped xt layout.

#define C_INQ 128
#define C_OUTQ 256
#define HDIM 56
#define WDIM 56
#define BDIM 32
#define HP 58
#define WP 58
#define HWPIX (HDIM * WDIM)                         // 3136
#define GSTRIDE (BDIM * HP * WP * 8)                // 861184 ushorts per c8-group
#define XT_ELEMS ((size_t)16 * GSTRIDE)             // 13,778,944
#define XT_BYTES (XT_ELEMS * 2)                     // 27,557,888

typedef __bf16 bf16x8 __attribute__((ext_vector_type(8)));
typedef unsigned short ushort8 __attribute__((ext_vector_type(8)));
typedef float floatx4 __attribute__((ext_vector_type(4)));

__device__ __forceinline__ unsigned short f2bf(float f) {
  union { float f; unsigned int u; } v; v.f = f;
  unsigned int u = v.u;
  unsigned int r = u + 0x7FFFu + ((u >> 16) & 1u);   // RNE (finite inputs)
  return (unsigned short)(r >> 16);
}
__device__ __forceinline__ unsigned int pack2(float a, float b) {
  return (unsigned int)f2bf(a) | ((unsigned int)f2bf(b) << 16);
}

// ---------------- kernel 1: x NCHW f32 -> xt [g][B][58][58][8] bf16, zero halo
// LDS-free: thread (g, w4) reads 8 coalesced float4 rows (channels g*8..g*8+7),
// packs in registers, stores 4 consecutive uint4 (coalesced).
__global__ __launch_bounds__(256) void pad_transpose_kernel(
    const float* __restrict__ x, unsigned short* __restrict__ xt) {
  const int blk = blockIdx.x;           // B*HP = 1856 blocks
  const int b = blk / HP;
  const int hp = blk - b * HP;
  const int t = threadIdx.x;
  uint4* __restrict__ xt4 = (uint4*)xt; // one uint4 = 8 channels of one pixel
  if (hp == 0 || hp == HP - 1) {        // top/bottom halo: 16 groups x 58 wp
    for (int i = t; i < 16 * WP; i += 256) {
      int g = i / WP, wp = i - g * WP;
      xt4[((size_t)(g * BDIM + b) * HP + hp) * WP + wp] = make_uint4(0, 0, 0, 0);
    }
    return;
  }
  const int h = hp - 1;
  if (t < 224) {                        // 16 groups x 14 float4 along w
    const int g = t / 14;
    const int w4 = (t - g * 14) * 4;    // 0..52
    const float* xp = x + ((size_t)b * C_INQ + g * 8) * HWPIX + h * WDIM + w4;
    float4 L0 = *(const float4*)(xp);
    float4 L1 = *(const float4*)(xp + HWPIX);
    float4 L2 = *(const float4*)(xp + 2 * HWPIX);
    float4 L3 = *(const float4*)(xp + 3 * HWPIX);
    float4 L4 = *(const float4*)(xp + 4 * HWPIX);
    float4 L5 = *(const float4*)(xp + 5 * HWPIX);
    float4 L6 = *(const float4*)(xp + 6 * HWPIX);
    float4 L7 = *(const float4*)(xp + 7 * HWPIX);
    uint4* dst = xt4 + ((size_t)(g * BDIM + b) * HP + hp) * WP + 1 + w4;
    dst[0] = make_uint4(pack2(L0.x, L1.x), pack2(L2.x, L3.x),
                        pack2(L4.x, L5.x), pack2(L6.x, L7.x));
    dst[1] = make_uint4(pack2(L0.y, L1.y), pack2(L2.y, L3.y),
                        pack2(L4.y, L5.y), pack2(L6.y, L7.y));
    dst[2] = make_uint4(pack2(L0.z, L1.z), pack2(L2.z, L3.z),
                        pack2(L4.z, L5.z), pack2(L6.z, L7.z));
    dst[3] = make_uint4(pack2(L0.w, L1.w), pack2(L2.w, L3.w),
                        pack2(L4.w, L5.w), pack2(L6.w, L7.w));
  } else {                              // 32 spare threads: left/right halo
    const int r = t - 224;              // 0..31 = 16 groups x {wp=0, wp=57}
    const int g = r >> 1;
    const int wp = (r & 1) * (WP - 1);
    xt4[((size_t)(g * BDIM + b) * HP + hp) * WP + wp] = make_uint4(0, 0, 0, 0);
  }
}

// ---------------- kernel 2: weight [1152][256] f32 -> wt [9][256][128] bf16
__global__ __launch_bounds__(256) void weight_transform_kernel(
    const float* __restrict__ w, unsigned short* __restrict__ wt) {
  const int bx = blockIdx.x;
  const int khw = bx >> 4;
  const int r4 = bx & 15;
  const int n0w = (r4 >> 2) * 64;
  const int c32 = (r4 & 3) * 32;
  const int t = threadIdx.x;
  __shared__ float lds[32 * 66];        // [c][n], stride 66
#pragma unroll
  for (int r = 0; r < 8; ++r) {
    int idx = r * 256 + t;              // 32*64 = 2048
    int n = idx & 63, c = idx >> 6;
    lds[c * 66 + n] = w[(size_t)((c32 + c) * 9 + khw) * C_OUTQ + n0w + n];
  }
  __syncthreads();
  {
    int n = t >> 2, c8 = (t & 3) * 8;
    const float* s = lds + c8 * 66 + n;
    uint4 o;
    o.x = pack2(s[0],   s[66]);
    o.y = pack2(s[132], s[198]);
    o.z = pack2(s[264], s[330]);
    o.w = pack2(s[396], s[462]);
    *(uint4*)(wt + (size_t)khw * (C_OUTQ * C_INQ) + (size_t)(n0w + n) * C_INQ + c32 + c8) = o;
  }
}

// ---------------- kernel 3: implicit GEMM, 128x256 tile, BK=32,
// triple-buffered LDS + counted vmcnt pipeline (loads never drained to 0
// in the main loop; 2 K-steps of loads stay in flight across barriers).
#define BM 128
#define BN 256
#define BK 32
#define STEPS 36                        // 9 khw * 4 c-quarters of 32

__global__ __launch_bounds__(256, 2) void conv_gemm_kernel(
    const unsigned short* __restrict__ xt,
    const unsigned short* __restrict__ wt,
    const float* __restrict__ bias,
    float* __restrict__ out) {
  // granule = 16B (8 ush). data(row,kpart) at slot kpart^(row&3) within row.
  __shared__ __align__(16) unsigned short ldsA[3 * BM * BK];  // 24KB
  __shared__ __align__(16) unsigned short ldsB[3 * BN * BK];  // 48KB

  const int t = threadIdx.x;
  const int lane = t & 63;
  const int wave = t >> 6;
  const int tile_m = blockIdx.x;        // 784

  // staging: A rounds 0..1, B rounds 0..3; round r stages granule g = r*256+t
  int gbaseA[2], gbaseB[4];
#pragma unroll
  for (int r = 0; r < 2; ++r) {
    int g = r * 256 + t;
    int row = g >> 2;
    int kpart = (g & 3) ^ (row & 3);    // swizzle inverse (pre-swizzled source)
    int pix = tile_m * BM + row;
    int b = pix / HWPIX;
    int p = pix - b * HWPIX;
    int h = p / WDIM;
    int w = p - h * WDIM;
    gbaseA[r] = kpart * GSTRIDE + ((b * HP + h) * WP + w) * 8;
  }
#pragma unroll
  for (int r = 0; r < 4; ++r) {
    int g = r * 256 + t;
    int row = g >> 2;                   // = n (BN == C_OUTQ)
    int kpart = (g & 3) ^ (row & 3);
    gbaseB[r] = row * C_INQ + kpart * 8;
  }

  // fragment geometry: wave grid 2x2 -> wave tile 64m x 128n
  const int wm = (wave >> 1) * 64;
  const int wn = (wave & 1) * 128;
  const int mrow = lane & 15;
  const int quad = lane >> 4;

  // LDS read offsets (ushort units), step-invariant
  int aoff[4], boff[8];
#pragma unroll
  for (int i = 0; i < 4; ++i) {
    int row = wm + i * 16 + mrow;
    aoff[i] = row * BK + ((quad ^ (row & 3)) * 8);
  }
#pragma unroll
  for (int j = 0; j < 8; ++j) {
    int row = wn + j * 16 + mrow;
    boff[j] = row * BK + ((quad ^ (row & 3)) * 8);
  }

  const int ldst = wave * 64 * 8;       // wave-uniform LDS dest (granules*8)

  floatx4 acc[4][8] = {};

  // stage K-step s2 into buffer bufc: 2 A loads + 4 B loads per thread
  auto stage = [&](int s2, int bufc) {
    const int khw = s2 >> 2;
    const int cq = s2 & 3;
    const int kh = khw / 3;
    const int kw = khw - kh * 3;
    const int koffA = cq * 4 * GSTRIDE + (kh * WP + kw) * 8;
    const int koffB = khw * (C_OUTQ * C_INQ) + cq * 32;
#pragma unroll
    for (int r = 0; r < 2; ++r)
      __builtin_amdgcn_global_load_lds(
          (const __attribute__((address_space(1))) unsigned int*)(xt + gbaseA[r] + koffA),
          (__attribute__((address_space(3))) unsigned int*)(ldsA + bufc * (BM * BK) + r * 2048 + ldst),
          16, 0, 0);
#pragma unroll
    for (int r = 0; r < 4; ++r)
      __builtin_amdgcn_global_load_lds(
          (const __attribute__((address_space(1))) unsigned int*)(wt + gbaseB[r] + koffB),
          (__attribute__((address_space(3))) unsigned int*)(ldsB + bufc * (BN * BK) + r * 2048 + ldst),
          16, 0, 0);
  };

  auto compute_step = [&](int bufc) {
    const unsigned short* A = ldsA + bufc * (BM * BK);
    const unsigned short* B = ldsB + bufc * (BN * BK);
    bf16x8 afr[4], bfr[8];
#pragma unroll
    for (int i = 0; i < 4; ++i)
      afr[i] = __builtin_bit_cast(bf16x8, *(const ushort8*)(A + aoff[i]));
#pragma unroll
    for (int j = 0; j < 8; ++j)
      bfr[j] = __builtin_bit_cast(bf16x8, *(const ushort8*)(B + boff[j]));
#pragma unroll
    for (int i = 0; i < 4; ++i)
#pragma unroll
      for (int j = 0; j < 8; ++j)
        acc[i][j] = __builtin_amdgcn_mfma_f32_16x16x32_bf16(afr[i], bfr[j], acc[i][j], 0, 0, 0);
  };

  // K_STEP: wait this buffer's loads (counted, own-wave), barrier (now ALL
  // waves' portions are in LDS), compute, barrier (all done reading), restage.
#define K_STEP(S, BUF, VM, DOSTAGE)                                  \
  {                                                                  \
    asm volatile("s_waitcnt vmcnt(" VM ")" ::: "memory");            \
    __builtin_amdgcn_s_barrier();                                    \
    compute_step(BUF);                                               \
    __builtin_amdgcn_s_barrier();                                    \
    if (DOSTAGE) stage((S) + 3, BUF);                                \
  }

  stage(0, 0);
  stage(1, 1);
  stage(2, 2);                          // 18 loads in flight

#pragma unroll 1
  for (int so = 0; so < 11; ++so) {     // s = 0..32: always 12 outstanding kept
    const int s = so * 3;
    K_STEP(s, 0, "12", true);
    K_STEP(s + 1, 1, "12", true);
    K_STEP(s + 2, 2, "12", true);
  }
  K_STEP(33, 0, "12", false);           // {34,35} stay in flight
  K_STEP(34, 1, "6", false);            // {35} stays in flight
  K_STEP(35, 2, "0", false);            // drain
#undef K_STEP

  // epilogue: C/D layout col(n) = lane&15, row(m) = quad*4 + reg.
  // 4 consecutive pixels per lane -> one float4 store (3136 % 4 == 0).
  float bv[8];
#pragma unroll
  for (int jn = 0; jn < 8; ++jn) bv[jn] = bias[wn + jn * 16 + mrow];
#pragma unroll
  for (int i = 0; i < 4; ++i) {
    const int mbase = tile_m * BM + wm + i * 16 + quad * 4;
    const int b = mbase / HWPIX;
    const int p = mbase - b * HWPIX;
    float* obase = out + (size_t)b * (C_OUTQ * HWPIX) + p;
#pragma unroll
    for (int jn = 0; jn < 8; ++jn) {
      const int ng = wn + jn * 16 + mrow;
      floatx4 v = acc[i][jn];
      v[0] += bv[jn]; v[1] += bv[jn]; v[2] += bv[jn]; v[3] += bv[jn];
      *(floatx4*)(obase + (size_t)ng * HWPIX) = v;
    }
  }
}

extern "C" void kernel_launch(void* const* d_in, const int* in_sizes, int n_in,
                              void* d_out, int out_size, void* d_ws, size_t ws_size,
                              hipStream_t stream) {
  const float* x    = (const float*)d_in[0];
  const float* w    = (const float*)d_in[1];
  const float* bias = (const float*)d_in[2];
  float* out = (float*)d_out;

  unsigned short* xt = (unsigned short*)d_ws;
  unsigned short* wt = (unsigned short*)((char*)d_ws + XT_BYTES);  // +589,824 B

  hipLaunchKernelGGL(pad_transpose_kernel, dim3(BDIM * HP), dim3(256), 0, stream, x, xt);
  hipLaunchKernelGGL(weight_transform_kernel, dim3(144), dim3(256), 0, stream, w, wt);
  hipLaunchKernelGGL(conv_gemm_kernel, dim3(784), dim3(256), 0, stream, xt, wt, bias, out);
}

// Round 2
// 232.136 us; speedup vs baseline: 1.0099x; 1.0099x over previous
//
#include <hip/hip_runtime.h>
#include <stdint.h>

// Conv2DUF: 3x3 s1 p1 conv, x[32][128][56][56] f32, weight[1152][256] f32
// (k = c*9 + kh*3 + kw), bias[256] f32 -> out[32][256][56][56] f32.
// bf16 implicit GEMM: M = 32*56*56 = 100352, N = 256, K = 1152.
//  ws: xt = bf16 x, GROUPED layout [c8grp(16)][B][58][58][8]  (halo = 0)
//      wt = bf16 weight reordered  [9][256][128]              (K-contiguous)
// R4: conv_gemm -> 256x256 tile, BK=64, 512 thr / 8 waves (2Mx4N, wave tile
//     128x64), ping-pong LDS 128KB, counted vmcnt(8) (never drains in main
//     loop), B-frags register-resident per K-tile, setprio around MFMA,
//     R2's proven conflict-free swizzle (kpart ^ row&7). Grid 392.
//     pad_transpose + weight_transform fused into one launch.

#define C_INQ 128
#define C_OUTQ 256
#define HDIM 56
#define WDIM 56
#define BDIM 32
#define HP 58
#define WP 58
#define HWPIX (HDIM * WDIM)                         // 3136
#define GSTRIDE (BDIM * HP * WP * 8)                // 861184 ushorts per c8-group
#define XT_ELEMS ((size_t)16 * GSTRIDE)             // 13,778,944
#define XT_BYTES (XT_ELEMS * 2)                     // 27,557,888

typedef __bf16 bf16x8 __attribute__((ext_vector_type(8)));
typedef unsigned short ushort8 __attribute__((ext_vector_type(8)));
typedef float floatx4 __attribute__((ext_vector_type(4)));

__device__ __forceinline__ unsigned short f2bf(float f) {
  union { float f; unsigned int u; } v; v.f = f;
  unsigned int u = v.u;
  unsigned int r = u + 0x7FFFu + ((u >> 16) & 1u);   // RNE (finite inputs)
  return (unsigned short)(r >> 16);
}
__device__ __forceinline__ unsigned int pack2(float a, float b) {
  return (unsigned int)f2bf(a) | ((unsigned int)f2bf(b) << 16);
}

// ---------------- kernel 1 (fused prep):
//   blocks [0, 1856):     x NCHW f32 -> xt [g][B][58][58][8] bf16, zero halo
//   blocks [1856, 2000):  weight [1152][256] f32 -> wt [9][256][128] bf16
#define PAD_BLOCKS (BDIM * HP)      // 1856
__global__ __launch_bounds__(256) void prep_kernel(
    const float* __restrict__ x, unsigned short* __restrict__ xt,
    const float* __restrict__ w, unsigned short* __restrict__ wt) {
  const int t = threadIdx.x;
  if (blockIdx.x < PAD_BLOCKS) {
    // ---- pad/transpose part (LDS-free streaming, grouped layout)
    const int blk = blockIdx.x;
    const int b = blk / HP;
    const int hp = blk - b * HP;
    uint4* __restrict__ xt4 = (uint4*)xt;  // one uint4 = 8 channels of a pixel
    if (hp == 0 || hp == HP - 1) {         // top/bottom halo rows
      for (int i = t; i < 16 * WP; i += 256) {
        int g = i / WP, wp = i - g * WP;
        xt4[((size_t)(g * BDIM + b) * HP + hp) * WP + wp] = make_uint4(0, 0, 0, 0);
      }
      return;
    }
    const int h = hp - 1;
    if (t < 224) {                         // 16 groups x 14 float4 along w
      const int g = t / 14;
      const int w4 = (t - g * 14) * 4;     // 0..52
      const float* xp = x + ((size_t)b * C_INQ + g * 8) * HWPIX + h * WDIM + w4;
      float4 L0 = *(const float4*)(xp);
      float4 L1 = *(const float4*)(xp + HWPIX);
      float4 L2 = *(const float4*)(xp + 2 * HWPIX);
      float4 L3 = *(const float4*)(xp + 3 * HWPIX);
      float4 L4 = *(const float4*)(xp + 4 * HWPIX);
      float4 L5 = *(const float4*)(xp + 5 * HWPIX);
      float4 L6 = *(const float4*)(xp + 6 * HWPIX);
      float4 L7 = *(const float4*)(xp + 7 * HWPIX);
      uint4* dst = xt4 + ((size_t)(g * BDIM + b) * HP + hp) * WP + 1 + w4;
      dst[0] = make_uint4(pack2(L0.x, L1.x), pack2(L2.x, L3.x),
                          pack2(L4.x, L5.x), pack2(L6.x, L7.x));
      dst[1] = make_uint4(pack2(L0.y, L1.y), pack2(L2.y, L3.y),
                          pack2(L4.y, L5.y), pack2(L6.y, L7.y));
      dst[2] = make_uint4(pack2(L0.z, L1.z), pack2(L2.z, L3.z),
                          pack2(L4.z, L5.z), pack2(L6.z, L7.z));
      dst[3] = make_uint4(pack2(L0.w, L1.w), pack2(L2.w, L3.w),
                          pack2(L4.w, L5.w), pack2(L6.w, L7.w));
    } else {                               // 32 spare threads: left/right halo
      const int r = t - 224;
      const int g = r >> 1;
      const int wp = (r & 1) * (WP - 1);
      xt4[((size_t)(g * BDIM + b) * HP + hp) * WP + wp] = make_uint4(0, 0, 0, 0);
    }
  } else {
    // ---- weight transform part
    const int bx = blockIdx.x - PAD_BLOCKS;  // 0..143
    const int khw = bx >> 4;
    const int r4 = bx & 15;
    const int n0w = (r4 >> 2) * 64;
    const int c32 = (r4 & 3) * 32;
    __shared__ float lds[32 * 66];           // [c][n], stride 66
#pragma unroll
    for (int r = 0; r < 8; ++r) {
      int idx = r * 256 + t;                 // 32*64 = 2048
      int n = idx & 63, c = idx >> 6;
      lds[c * 66 + n] = w[(size_t)((c32 + c) * 9 + khw) * C_OUTQ + n0w + n];
    }
    __syncthreads();
    {
      int n = t >> 2, c8 = (t & 3) * 8;
      const float* s = lds + c8 * 66 + n;
      uint4 o;
      o.x = pack2(s[0],   s[66]);
      o.y = pack2(s[132], s[198]);
      o.z = pack2(s[264], s[330]);
      o.w = pack2(s[396], s[462]);
      *(uint4*)(wt + (size_t)khw * (C_OUTQ * C_INQ) + (size_t)(n0w + n) * C_INQ + c32 + c8) = o;
    }
  }
}

// ---------------- kernel 2: implicit GEMM, 256x256 tile, BK=64, 8 waves,
// ping-pong LDS + counted vmcnt(8); B-frags register-resident per K-tile.
#define BM 256
#define BN 256
#define BK 64
#define NT 18                            // K-tiles: 9 khw x 2 c-halves of 64

__global__ __launch_bounds__(512, 2) void conv_gemm_kernel(
    const unsigned short* __restrict__ xt,
    const unsigned short* __restrict__ wt,
    const float* __restrict__ bias,
    float* __restrict__ out) {
  // granule = 16B (8 ush). data(row,kpart) at slot kpart^(row&7) within row.
  __shared__ __align__(16) unsigned short ldsA[2 * BM * BK];  // 64KB
  __shared__ __align__(16) unsigned short ldsB[2 * BN * BK];  // 64KB

  const int t = threadIdx.x;             // 0..511
  const int lane = t & 63;
  const int wave = t >> 6;               // 0..7
  const int tile_m = blockIdx.x;         // 392

  // staging: A rounds 0..3, B rounds 0..3; round r stages granule g = r*512+t
  int gbaseA[4], gbaseB[4];
#pragma unroll
  for (int r = 0; r < 4; ++r) {
    int g = r * 512 + t;
    int row = g >> 3;                    // 0..255
    int kpart = (g & 7) ^ (row & 7);     // swizzle inverse (pre-swizzled src)
    int pix = tile_m * BM + row;
    int b = pix / HWPIX;
    int p = pix - b * HWPIX;
    int h = p / WDIM;
    int w = p - h * WDIM;
    gbaseA[r] = kpart * GSTRIDE + ((b * HP + h) * WP + w) * 8;
  }
#pragma unroll
  for (int r = 0; r < 4; ++r) {
    int g = r * 512 + t;
    int n = g >> 3;                      // 0..255 (BN == C_OUTQ)
    int kpart = (g & 7) ^ (n & 7);
    gbaseB[r] = n * C_INQ + kpart * 8;
  }

  // wave grid 2M x 4N -> wave tile 128m x 64n
  const int wm = (wave >> 2) * 128;
  const int wn = (wave & 3) * 64;
  const int mrow = lane & 15;
  const int quad = lane >> 4;
  const int xorv = mrow & 7;
  const int kx0 = (quad ^ xorv) * 8;         // k-sub 0 granule
  const int kx1 = ((4 + quad) ^ xorv) * 8;   // k-sub 1 granule

  floatx4 acc[8][4] = {};

  // stage K-tile kt into buffer buf: 4 A + 4 B global_load_lds per thread
  auto stage = [&](int kt, int buf) {
    const int khw = kt >> 1;
    const int chalf = kt & 1;
    const int kh = khw / 3;
    const int kw = khw - kh * 3;
    const int koffA = chalf * 8 * GSTRIDE + (kh * WP + kw) * 8;
    const int koffB = khw * (C_OUTQ * C_INQ) + chalf * 64;
    const int ldst = t * 8;              // per-thread linear granule dest
#pragma unroll
    for (int r = 0; r < 4; ++r)
      __builtin_amdgcn_global_load_lds(
          (const __attribute__((address_space(1))) unsigned int*)(xt + gbaseA[r] + koffA),
          (__attribute__((address_space(3))) unsigned int*)(ldsA + buf * (BM * BK) + r * 4096 + ldst),
          16, 0, 0);
#pragma unroll
    for (int r = 0; r < 4; ++r)
      __builtin_amdgcn_global_load_lds(
          (const __attribute__((address_space(1))) unsigned int*)(wt + gbaseB[r] + koffB),
          (__attribute__((address_space(3))) unsigned int*)(ldsB + buf * (BN * BK) + r * 4096 + ldst),
          16, 0, 0);
  };

  // compute one K-tile: B-frags loaded once into regs, then 4 m-pair phases
  auto compute_tile = [&](int buf) {
    const unsigned short* A = ldsA + buf * (BM * BK);
    const unsigned short* B = ldsB + buf * (BN * BK);
    bf16x8 bfr[4][2];
#pragma unroll
    for (int j = 0; j < 4; ++j) {
      const unsigned short* br = B + (wn + j * 16 + mrow) * BK;
      bfr[j][0] = __builtin_bit_cast(bf16x8, *(const ushort8*)(br + kx0));
      bfr[j][1] = __builtin_bit_cast(bf16x8, *(const ushort8*)(br + kx1));
    }
#pragma unroll
    for (int p = 0; p < 4; ++p) {
      bf16x8 af[2][2];
#pragma unroll
      for (int i2 = 0; i2 < 2; ++i2) {
        const unsigned short* ar = A + (wm + (p * 2 + i2) * 16 + mrow) * BK;
        af[i2][0] = __builtin_bit_cast(bf16x8, *(const ushort8*)(ar + kx0));
        af[i2][1] = __builtin_bit_cast(bf16x8, *(const ushort8*)(ar + kx1));
      }
      __builtin_amdgcn_s_setprio(1);
#pragma unroll
      for (int i2 = 0; i2 < 2; ++i2)
#pragma unroll
        for (int u = 0; u < 2; ++u)
#pragma unroll
          for (int j = 0; j < 4; ++j)
            acc[p * 2 + i2][j] = __builtin_amdgcn_mfma_f32_16x16x32_bf16(
                af[i2][u], bfr[j][u], acc[p * 2 + i2][j], 0, 0, 0);
      __builtin_amdgcn_s_setprio(0);
    }
  };

  // K_STEP: counted wait (own-wave stage(T) landed), barrier (ALL waves'
  // portions valid), compute, barrier (all done reading), restage buffer.
#define K_STEP(T, BUF, VM, DOSTAGE)                                  \
  {                                                                  \
    asm volatile("s_waitcnt vmcnt(" VM ")" ::: "memory");            \
    __builtin_amdgcn_s_barrier();                                    \
    compute_tile(BUF);                                               \
    __builtin_amdgcn_s_barrier();                                    \
    if (DOSTAGE) stage((T) + 2, BUF);                                \
  }

  stage(0, 0);
  stage(1, 1);                           // 16 loads in flight per wave

#pragma unroll 1
  for (int tt = 0; tt < 16; tt += 2) {   // tiles 0..15: keep 8 outstanding
    K_STEP(tt, 0, "8", true);
    K_STEP(tt + 1, 1, "8", true);
  }
  K_STEP(16, 0, "8", false);             // stage(17) stays in flight
  K_STEP(17, 1, "0", false);             // final drain
#undef K_STEP

  // epilogue: C/D layout col(n) = lane&15, row(m) = quad*4 + reg.
  // 4 consecutive pixels per lane -> one float4 store (3136 % 4 == 0).
  float bv[4];
#pragma unroll
  for (int j = 0; j < 4; ++j) bv[j] = bias[wn + j * 16 + mrow];
#pragma unroll
  for (int i = 0; i < 8; ++i) {
    const int mbase = tile_m * BM + wm + i * 16 + quad * 4;
    const int b = mbase / HWPIX;
    const int p = mbase - b * HWPIX;
    float* obase = out + (size_t)b * (C_OUTQ * HWPIX) + p;
#pragma unroll
    for (int j = 0; j < 4; ++j) {
      const int ng = wn + j * 16 + mrow;
      floatx4 v = acc[i][j];
      v[0] += bv[j]; v[1] += bv[j]; v[2] += bv[j]; v[3] += bv[j];
      *(floatx4*)(obase + (size_t)ng * HWPIX) = v;
    }
  }
}

extern "C" void kernel_launch(void* const* d_in, const int* in_sizes, int n_in,
                              void* d_out, int out_size, void* d_ws, size_t ws_size,
                              hipStream_t stream) {
  const float* x    = (const float*)d_in[0];
  const float* w    = (const float*)d_in[1];
  const float* bias = (const float*)d_in[2];
  float* out = (float*)d_out;

  unsigned short* xt = (unsigned short*)d_ws;
  unsigned short* wt = (unsigned short*)((char*)d_ws + XT_BYTES);  // +589,824 B

  hipLaunchKernelGGL(prep_kernel, dim3(PAD_BLOCKS + 144), dim3(256), 0, stream,
                     x, xt, w, wt);
  hipLaunchKernelGGL(conv_gemm_kernel, dim3(392), dim3(512), 0, stream,
                     xt, wt, bias, out);
}

// Round 3
// 228.751 us; speedup vs baseline: 1.0248x; 1.0148x over previous
//
#include <hip/hip_runtime.h>
#include <stdint.h>

// Conv2DUF: 3x3 s1 p1 conv, x[32][128][56][56] f32, weight[1152][256] f32
// (k = c*9 + kh*3 + kw), bias[256] f32 -> out[32][256][56][56] f32.
// bf16 implicit GEMM: M = 32*56*56 = 100352, N = 256, K = 1152.
//  ws: xt = bf16 x, GROUPED layout [c8grp(16)][B][58][58][8]  (halo = 0)
//      wt = bf16 weight reordered  [9][256][128]              (K-contiguous)
// R5: conv_gemm -> m201-style 8-phase schedule on the 256x256/BK=64/8-wave
//     geometry: 4 phases per K-tile (one C-quadrant x 16 MFMA each), per-phase
//     {ds_read subtile || stage issue -> barrier -> setprio MFMA -> barrier},
//     B-halves register-resident, staging issued 2+ phases before the single
//     per-K-tile vmcnt(0). Swizzle kpart^(row&7) (0 conflicts, proven R2/R4).

#define C_INQ 128
#define C_OUTQ 256
#define HDIM 56
#define WDIM 56
#define BDIM 32
#define HP 58
#define WP 58
#define HWPIX (HDIM * WDIM)                         // 3136
#define GSTRIDE (BDIM * HP * WP * 8)                // 861184 ushorts per c8-group
#define XT_ELEMS ((size_t)16 * GSTRIDE)             // 13,778,944
#define XT_BYTES (XT_ELEMS * 2)                     // 27,557,888

typedef __bf16 bf16x8 __attribute__((ext_vector_type(8)));
typedef unsigned short ushort8 __attribute__((ext_vector_type(8)));
typedef float floatx4 __attribute__((ext_vector_type(4)));

__device__ __forceinline__ unsigned short f2bf(float f) {
  union { float f; unsigned int u; } v; v.f = f;
  unsigned int u = v.u;
  unsigned int r = u + 0x7FFFu + ((u >> 16) & 1u);   // RNE (finite inputs)
  return (unsigned short)(r >> 16);
}
__device__ __forceinline__ unsigned int pack2(float a, float b) {
  return (unsigned int)f2bf(a) | ((unsigned int)f2bf(b) << 16);
}

// ---------------- kernel 1 (fused prep):
//   blocks [0, 1856):     x NCHW f32 -> xt [g][B][58][58][8] bf16, zero halo
//   blocks [1856, 2000):  weight [1152][256] f32 -> wt [9][256][128] bf16
#define PAD_BLOCKS (BDIM * HP)      // 1856
__global__ __launch_bounds__(256) void prep_kernel(
    const float* __restrict__ x, unsigned short* __restrict__ xt,
    const float* __restrict__ w, unsigned short* __restrict__ wt) {
  const int t = threadIdx.x;
  if (blockIdx.x < PAD_BLOCKS) {
    // ---- pad/transpose part (LDS-free streaming, grouped layout)
    const int blk = blockIdx.x;
    const int b = blk / HP;
    const int hp = blk - b * HP;
    uint4* __restrict__ xt4 = (uint4*)xt;  // one uint4 = 8 channels of a pixel
    if (hp == 0 || hp == HP - 1) {         // top/bottom halo rows
      for (int i = t; i < 16 * WP; i += 256) {
        int g = i / WP, wp = i - g * WP;
        xt4[((size_t)(g * BDIM + b) * HP + hp) * WP + wp] = make_uint4(0, 0, 0, 0);
      }
      return;
    }
    const int h = hp - 1;
    if (t < 224) {                         // 16 groups x 14 float4 along w
      const int g = t / 14;
      const int w4 = (t - g * 14) * 4;     // 0..52
      const float* xp = x + ((size_t)b * C_INQ + g * 8) * HWPIX + h * WDIM + w4;
      float4 L0 = *(const float4*)(xp);
      float4 L1 = *(const float4*)(xp + HWPIX);
      float4 L2 = *(const float4*)(xp + 2 * HWPIX);
      float4 L3 = *(const float4*)(xp + 3 * HWPIX);
      float4 L4 = *(const float4*)(xp + 4 * HWPIX);
      float4 L5 = *(const float4*)(xp + 5 * HWPIX);
      float4 L6 = *(const float4*)(xp + 6 * HWPIX);
      float4 L7 = *(const float4*)(xp + 7 * HWPIX);
      uint4* dst = xt4 + ((size_t)(g * BDIM + b) * HP + hp) * WP + 1 + w4;
      dst[0] = make_uint4(pack2(L0.x, L1.x), pack2(L2.x, L3.x),
                          pack2(L4.x, L5.x), pack2(L6.x, L7.x));
      dst[1] = make_uint4(pack2(L0.y, L1.y), pack2(L2.y, L3.y),
                          pack2(L4.y, L5.y), pack2(L6.y, L7.y));
      dst[2] = make_uint4(pack2(L0.z, L1.z), pack2(L2.z, L3.z),
                          pack2(L4.z, L5.z), pack2(L6.z, L7.z));
      dst[3] = make_uint4(pack2(L0.w, L1.w), pack2(L2.w, L3.w),
                          pack2(L4.w, L5.w), pack2(L6.w, L7.w));
    } else {                               // 32 spare threads: left/right halo
      const int r = t - 224;
      const int g = r >> 1;
      const int wp = (r & 1) * (WP - 1);
      xt4[((size_t)(g * BDIM + b) * HP + hp) * WP + wp] = make_uint4(0, 0, 0, 0);
    }
  } else {
    // ---- weight transform part
    const int bx = blockIdx.x - PAD_BLOCKS;  // 0..143
    const int khw = bx >> 4;
    const int r4 = bx & 15;
    const int n0w = (r4 >> 2) * 64;
    const int c32 = (r4 & 3) * 32;
    __shared__ float lds[32 * 66];           // [c][n], stride 66
#pragma unroll
    for (int r = 0; r < 8; ++r) {
      int idx = r * 256 + t;                 // 32*64 = 2048
      int n = idx & 63, c = idx >> 6;
      lds[c * 66 + n] = w[(size_t)((c32 + c) * 9 + khw) * C_OUTQ + n0w + n];
    }
    __syncthreads();
    {
      int n = t >> 2, c8 = (t & 3) * 8;
      const float* s = lds + c8 * 66 + n;
      uint4 o;
      o.x = pack2(s[0],   s[66]);
      o.y = pack2(s[132], s[198]);
      o.z = pack2(s[264], s[330]);
      o.w = pack2(s[396], s[462]);
      *(uint4*)(wt + (size_t)khw * (C_OUTQ * C_INQ) + (size_t)(n0w + n) * C_INQ + c32 + c8) = o;
    }
  }
}

// ---------------- kernel 2: implicit GEMM, 256x256 tile, BK=64, 8 waves,
// 8-phase schedule (4 phases/K-tile), dbuf LDS, single counted vmcnt/K-tile.
#define BM 256
#define BN 256
#define BK 64
#define NT 18                            // K-tiles: 9 khw x 2 c-halves of 64
#define LDS_HALF 8192                    // ushorts: 128 rows x 64
#define LDS_BUF  16384                   // ushorts: 256 rows x 64

__global__ __launch_bounds__(512, 2) void conv_gemm_kernel(
    const unsigned short* __restrict__ xt,
    const unsigned short* __restrict__ wt,
    const float* __restrict__ bias,
    float* __restrict__ out) {
  // granule = 16B (8 ush). data(row,kpart) at slot kpart^(row&7) within row.
  __shared__ __align__(16) unsigned short ldsA[2 * BM * BK];  // 64KB
  __shared__ __align__(16) unsigned short ldsB[2 * BN * BK];  // 64KB

  const int t = threadIdx.x;             // 0..511
  const int lane = t & 63;
  const int wave = t >> 6;               // 0..7
  const int tile_m = blockIdx.x;         // 392

  // staging geometry: half-tile = 128 rows x 64k = 1024 granules
  //  -> 2 loads/thread/half-tile; granule g = r*512 + t.
  int gbaseA[2][2], gbaseB[2][2];        // [half][r]
#pragma unroll
  for (int r = 0; r < 2; ++r) {
    int g = r * 512 + t;
    int rl = g >> 3;                     // 0..127 row within half
    int kp = (g & 7) ^ (rl & 7);         // swizzle inverse ((rl+128)&7 == rl&7)
#pragma unroll
    for (int h = 0; h < 2; ++h) {
      int pix = tile_m * BM + h * 128 + rl;
      int b = pix / HWPIX;
      int p = pix - b * HWPIX;
      int hh = p / WDIM;
      int ww = p - hh * WDIM;
      gbaseA[h][r] = kp * GSTRIDE + ((b * HP + hh) * WP + ww) * 8;
      gbaseB[h][r] = (h * 128 + rl) * C_INQ + kp * 8;
    }
  }

  // wave grid 2M x 4N -> wave tile 128m x 64n
  const int wm = (wave >> 2) * 128;
  const int wn = (wave & 3) * 64;
  const int mrow = lane & 15;
  const int quad = lane >> 4;
  const int xorv = mrow & 7;
  const int kx0 = (quad ^ xorv) * 8;         // k-sub 0 granule offset (ush)
  const int kx1 = ((4 + quad) ^ xorv) * 8;   // k-sub 1
  int abase[8], bbase[4];
#pragma unroll
  for (int i = 0; i < 8; ++i) abase[i] = (wm + i * 16 + mrow) * BK;
#pragma unroll
  for (int j = 0; j < 4; ++j) bbase[j] = (wn + j * 16 + mrow) * BK;

  floatx4 acc[8][4] = {};

  auto stageA = [&](int kt, int buf) {   // A half-tiles of K-tile kt -> buf
    const int khw = kt >> 1, ch = kt & 1;
    const int kh = khw / 3, kw = khw - kh * 3;
    const int koff = ch * 8 * GSTRIDE + (kh * WP + kw) * 8;
    unsigned short* base = ldsA + buf * LDS_BUF;
#pragma unroll
    for (int h = 0; h < 2; ++h)
#pragma unroll
      for (int r = 0; r < 2; ++r)
        __builtin_amdgcn_global_load_lds(
            (const __attribute__((address_space(1))) unsigned int*)(xt + gbaseA[h][r] + koff),
            (__attribute__((address_space(3))) unsigned int*)(base + h * LDS_HALF + r * 4096 + t * 8),
            16, 0, 0);
  };
  auto stageB = [&](int kt, int buf) {   // B half-tiles of K-tile kt -> buf
    const int khw = kt >> 1, ch = kt & 1;
    const int koff = khw * (C_OUTQ * C_INQ) + ch * 64;
    unsigned short* base = ldsB + buf * LDS_BUF;
#pragma unroll
    for (int h = 0; h < 2; ++h)
#pragma unroll
      for (int r = 0; r < 2; ++r)
        __builtin_amdgcn_global_load_lds(
            (const __attribute__((address_space(1))) unsigned int*)(wt + gbaseB[h][r] + koff),
            (__attribute__((address_space(3))) unsigned int*)(base + h * LDS_HALF + r * 4096 + t * 8),
            16, 0, 0);
  };

#define BC8(p) __builtin_bit_cast(bf16x8, *(const ushort8*)(p))
#define BARW __builtin_amdgcn_s_barrier()

  // One K-tile = 4 phases, each: {ds_read subtile || stage} BAR {16 MFMA} BAR.
  // Quadrant order (mh,nh): (0,0) (0,1) (1,1) (1,0) — B-halves stay in regs.
  auto ktile = [&](int T, int buf, bool dostage) {
    const unsigned short* Ab = ldsA + buf * LDS_BUF;
    const unsigned short* Bb = ldsB + buf * LDS_BUF;
    bf16x8 af[4][2], b0[2][2], b1[2][2];
    // ---- P0: read A-half0 + B-half0; stage A(T+1); MFMA Q(0,0)
#pragma unroll
    for (int i = 0; i < 4; ++i) {
      af[i][0] = BC8(Ab + abase[i] + kx0);
      af[i][1] = BC8(Ab + abase[i] + kx1);
    }
#pragma unroll
    for (int j = 0; j < 2; ++j) {
      b0[j][0] = BC8(Bb + bbase[j] + kx0);
      b0[j][1] = BC8(Bb + bbase[j] + kx1);
    }
    if (dostage) stageA(T + 1, buf ^ 1);
    BARW;
    __builtin_amdgcn_s_setprio(1);
#pragma unroll
    for (int u = 0; u < 2; ++u)
#pragma unroll
      for (int i = 0; i < 4; ++i)
#pragma unroll
        for (int j = 0; j < 2; ++j)
          acc[i][j] = __builtin_amdgcn_mfma_f32_16x16x32_bf16(af[i][u], b0[j][u], acc[i][j], 0, 0, 0);
    __builtin_amdgcn_s_setprio(0);
    BARW;
    // ---- P1: read B-half1; stage B(T+1); MFMA Q(0,1)
#pragma unroll
    for (int j = 0; j < 2; ++j) {
      b1[j][0] = BC8(Bb + bbase[2 + j] + kx0);
      b1[j][1] = BC8(Bb + bbase[2 + j] + kx1);
    }
    if (dostage) stageB(T + 1, buf ^ 1);
    BARW;
    __builtin_amdgcn_s_setprio(1);
#pragma unroll
    for (int u = 0; u < 2; ++u)
#pragma unroll
      for (int i = 0; i < 4; ++i)
#pragma unroll
        for (int j = 0; j < 2; ++j)
          acc[i][2 + j] = __builtin_amdgcn_mfma_f32_16x16x32_bf16(af[i][u], b1[j][u], acc[i][2 + j], 0, 0, 0);
    __builtin_amdgcn_s_setprio(0);
    BARW;
    // ---- P2: read A-half1; MFMA Q(1,1)
#pragma unroll
    for (int i = 0; i < 4; ++i) {
      af[i][0] = BC8(Ab + abase[4 + i] + kx0);
      af[i][1] = BC8(Ab + abase[4 + i] + kx1);
    }
    BARW;
    __builtin_amdgcn_s_setprio(1);
#pragma unroll
    for (int u = 0; u < 2; ++u)
#pragma unroll
      for (int i = 0; i < 4; ++i)
#pragma unroll
        for (int j = 0; j < 2; ++j)
          acc[4 + i][2 + j] = __builtin_amdgcn_mfma_f32_16x16x32_bf16(af[i][u], b1[j][u], acc[4 + i][2 + j], 0, 0, 0);
    __builtin_amdgcn_s_setprio(0);
    BARW;
    // ---- P3: no reads (b0 in regs); MFMA Q(1,0); K-tile boundary vmcnt
#pragma unroll
    for (int u = 0; u < 2; ++u)
#pragma unroll
      for (int i = 0; i < 4; ++i)
#pragma unroll
        for (int j = 0; j < 2; ++j)
          acc[4 + i][j] = __builtin_amdgcn_mfma_f32_16x16x32_bf16(af[i][u], b0[j][u], acc[4 + i][j], 0, 0, 0);
    if (dostage) asm volatile("s_waitcnt vmcnt(0)" ::: "memory");
    BARW;
  };

  // prologue: stage K-tile 0, drain once (cold), enter lockstep
  stageA(0, 0);
  stageB(0, 0);
  asm volatile("s_waitcnt vmcnt(0)" ::: "memory");
  BARW;

#pragma unroll 1
  for (int tt = 0; tt < 16; tt += 2) {
    ktile(tt, 0, true);
    ktile(tt + 1, 1, true);
  }
  ktile(16, 0, true);
  ktile(17, 1, false);

#undef BC8
#undef BARW

  // epilogue: C/D layout col(n) = lane&15, row(m) = quad*4 + reg.
  // 4 consecutive pixels per lane -> one float4 store (3136 % 4 == 0).
  float bv[4];
#pragma unroll
  for (int j = 0; j < 4; ++j) bv[j] = bias[wn + j * 16 + mrow];
#pragma unroll
  for (int i = 0; i < 8; ++i) {
    const int mbase = tile_m * BM + wm + i * 16 + quad * 4;
    const int b = mbase / HWPIX;
    const int p = mbase - b * HWPIX;
    float* obase = out + (size_t)b * (C_OUTQ * HWPIX) + p;
#pragma unroll
    for (int j = 0; j < 4; ++j) {
      const int ng = wn + j * 16 + mrow;
      floatx4 v = acc[i][j];
      v[0] += bv[j]; v[1] += bv[j]; v[2] += bv[j]; v[3] += bv[j];
      *(floatx4*)(obase + (size_t)ng * HWPIX) = v;
    }
  }
}

extern "C" void kernel_launch(void* const* d_in, const int* in_sizes, int n_in,
                              void* d_out, int out_size, void* d_ws, size_t ws_size,
                              hipStream_t stream) {
  const float* x    = (const float*)d_in[0];
  const float* w    = (const float*)d_in[1];
  const float* bias = (const float*)d_in[2];
  float* out = (float*)d_out;

  unsigned short* xt = (unsigned short*)d_ws;
  unsigned short* wt = (unsigned short*)((char*)d_ws + XT_BYTES);  // +589,824 B

  hipLaunchKernelGGL(prep_kernel, dim3(PAD_BLOCKS + 144), dim3(256), 0, stream,
                     x, xt, w, wt);
  hipLaunchKernelGGL(conv_gemm_kernel, dim3(392), dim3(512), 0, stream,
                     xt, wt, bias, out);
}

// Round 4
// 212.827 us; speedup vs baseline: 1.1015x; 1.0748x over previous
//
#include <hip/hip_runtime.h>
#include <stdint.h>

// Conv2DUF: 3x3 s1 p1 conv, x[32][128][56][56] f32, weight[1152][256] f32
// (k = c*9 + kh*3 + kw), bias[256] f32 -> out[32][256][56][56] f32.
// bf16 implicit GEMM: M = 32*56*56 = 100352, N = 256, K = 1152.
//  ws: xt = bf16 x, GROUPED layout [c8grp(16)][B][58][58][8]  (halo = 0)
//      wt = bf16 weight reordered  [9][256][128]              (K-contiguous)
// R6: A-footprint-resident GEMM. Tile = 1 image x 4 output rows x full width
//     (BM=224, grid 448, never straddles images). The block's entire xt
//     footprint (16 grp x 6 padded rows x 58 px = 90KB) is staged to LDS ONCE;
//     all 18 K-tiles read A at shifted (kh,kw) offsets -> kills the 5.7x A
//     re-staging redundancy that made every prior round load-service-bound.
//     B (wt, L2-hot) double-buffered 2x32KB, counted vmcnt(4), 2 barriers/kt.
//     Bijective XCD swizzle: each XCD owns 4 whole images (L2-sized slice).

#define C_INQ 128
#define C_OUTQ 256
#define HDIM 56
#define WDIM 56
#define BDIM 32
#define HP 58
#define WP 58
#define HWPIX (HDIM * WDIM)                         // 3136
#define GSTRIDE (BDIM * HP * WP * 8)                // 861184 ushorts per c8-group
#define XT_ELEMS ((size_t)16 * GSTRIDE)             // 13,778,944
#define XT_BYTES (XT_ELEMS * 2)                     // 27,557,888

typedef __bf16 bf16x8 __attribute__((ext_vector_type(8)));
typedef unsigned short ushort8 __attribute__((ext_vector_type(8)));
typedef float floatx4 __attribute__((ext_vector_type(4)));

__device__ __forceinline__ unsigned short f2bf(float f) {
  union { float f; unsigned int u; } v; v.f = f;
  unsigned int u = v.u;
  unsigned int r = u + 0x7FFFu + ((u >> 16) & 1u);   // RNE (finite inputs)
  return (unsigned short)(r >> 16);
}
__device__ __forceinline__ unsigned int pack2(float a, float b) {
  return (unsigned int)f2bf(a) | ((unsigned int)f2bf(b) << 16);
}

// ---------------- kernel 1 (fused prep):
//   blocks [0, 1856):     x NCHW f32 -> xt [g][B][58][58][8] bf16, zero halo
//   blocks [1856, 2000):  weight [1152][256] f32 -> wt [9][256][128] bf16
#define PAD_BLOCKS (BDIM * HP)      // 1856
__global__ __launch_bounds__(256) void prep_kernel(
    const float* __restrict__ x, unsigned short* __restrict__ xt,
    const float* __restrict__ w, unsigned short* __restrict__ wt) {
  const int t = threadIdx.x;
  if (blockIdx.x < PAD_BLOCKS) {
    const int blk = blockIdx.x;
    const int b = blk / HP;
    const int hp = blk - b * HP;
    uint4* __restrict__ xt4 = (uint4*)xt;  // one uint4 = 8 channels of a pixel
    if (hp == 0 || hp == HP - 1) {         // top/bottom halo rows
      for (int i = t; i < 16 * WP; i += 256) {
        int g = i / WP, wp = i - g * WP;
        xt4[((size_t)(g * BDIM + b) * HP + hp) * WP + wp] = make_uint4(0, 0, 0, 0);
      }
      return;
    }
    const int h = hp - 1;
    if (t < 224) {                         // 16 groups x 14 float4 along w
      const int g = t / 14;
      const int w4 = (t - g * 14) * 4;     // 0..52
      const float* xp = x + ((size_t)b * C_INQ + g * 8) * HWPIX + h * WDIM + w4;
      float4 L0 = *(const float4*)(xp);
      float4 L1 = *(const float4*)(xp + HWPIX);
      float4 L2 = *(const float4*)(xp + 2 * HWPIX);
      float4 L3 = *(const float4*)(xp + 3 * HWPIX);
      float4 L4 = *(const float4*)(xp + 4 * HWPIX);
      float4 L5 = *(const float4*)(xp + 5 * HWPIX);
      float4 L6 = *(const float4*)(xp + 6 * HWPIX);
      float4 L7 = *(const float4*)(xp + 7 * HWPIX);
      uint4* dst = xt4 + ((size_t)(g * BDIM + b) * HP + hp) * WP + 1 + w4;
      dst[0] = make_uint4(pack2(L0.x, L1.x), pack2(L2.x, L3.x),
                          pack2(L4.x, L5.x), pack2(L6.x, L7.x));
      dst[1] = make_uint4(pack2(L0.y, L1.y), pack2(L2.y, L3.y),
                          pack2(L4.y, L5.y), pack2(L6.y, L7.y));
      dst[2] = make_uint4(pack2(L0.z, L1.z), pack2(L2.z, L3.z),
                          pack2(L4.z, L5.z), pack2(L6.z, L7.z));
      dst[3] = make_uint4(pack2(L0.w, L1.w), pack2(L2.w, L3.w),
                          pack2(L4.w, L5.w), pack2(L6.w, L7.w));
    } else {                               // 32 spare threads: left/right halo
      const int r = t - 224;
      const int g = r >> 1;
      const int wp = (r & 1) * (WP - 1);
      xt4[((size_t)(g * BDIM + b) * HP + hp) * WP + wp] = make_uint4(0, 0, 0, 0);
    }
  } else {
    const int bx = blockIdx.x - PAD_BLOCKS;  // 0..143
    const int khw = bx >> 4;
    const int r4 = bx & 15;
    const int n0w = (r4 >> 2) * 64;
    const int c32 = (r4 & 3) * 32;
    __shared__ float lds[32 * 66];           // [c][n], stride 66
#pragma unroll
    for (int r = 0; r < 8; ++r) {
      int idx = r * 256 + t;                 // 32*64 = 2048
      int n = idx & 63, c = idx >> 6;
      lds[c * 66 + n] = w[(size_t)((c32 + c) * 9 + khw) * C_OUTQ + n0w + n];
    }
    __syncthreads();
    {
      int n = t >> 2, c8 = (t & 3) * 8;
      const float* s = lds + c8 * 66 + n;
      uint4 o;
      o.x = pack2(s[0],   s[66]);
      o.y = pack2(s[132], s[198]);
      o.z = pack2(s[264], s[330]);
      o.w = pack2(s[396], s[462]);
      *(uint4*)(wt + (size_t)khw * (C_OUTQ * C_INQ) + (size_t)(n0w + n) * C_INQ + c32 + c8) = o;
    }
  }
}

// ---------------- kernel 2: A-footprint-resident implicit GEMM.
// Tile: image b, output rows h0..h0+3, all 56 w  (BM = 224). BN = 256, BK=64.
// 8 waves (2M x 4N): wave tile 112m x 64n -> acc[7][4].
// LDS: A footprint 16 regions x 352 granules (348 = 6x58 used) = 90,112 B,
//      region stride 5632 B = 44*128 (uniform bank phase, zero extra conflict);
//      B double-buffer 2 x 2048 granules (xor-swizzled rows) = 65,536 B.
#define REGG 352                          // granules per A-region (padded)
#define AGRAN (16 * REGG)                 // 5632 staged granules (11 rounds)
#define NTILE 18                          // kt = khw*2 + chalf

__global__ __launch_bounds__(512, 2) void conv_gemm_kernel(
    const unsigned short* __restrict__ xt,
    const unsigned short* __restrict__ wt,
    const float* __restrict__ bias,
    float* __restrict__ out) {
  __shared__ __align__(16) unsigned short ldsA[AGRAN * 8];     // 90,112 B
  __shared__ __align__(16) unsigned short ldsB[2 * 2048 * 8];  // 65,536 B

  const int t = threadIdx.x;              // 0..511
  const int lane = t & 63;
  const int wave = t >> 6;
  // bijective XCD swizzle (448 % 8 == 0): XCD k owns blocks [k*56,(k+1)*56)
  const int bid = ((int)blockIdx.x & 7) * 56 + ((int)blockIdx.x >> 3);
  const int b = bid / 14;
  const int ht = bid - b * 14;
  const int hp0 = ht * 4;                 // padded-row base of footprint

  // B staging bases (granule g = r*512+t; row = g>>3; slot = g&7 xor row&7)
  int gbaseB[4];
#pragma unroll
  for (int r = 0; r < 4; ++r) {
    int g = r * 512 + t;
    int row = g >> 3;                     // 0..255
    int kp = (g & 7) ^ (row & 7);
    gbaseB[r] = row * C_INQ + kp * 8;
  }

  const int wm = (wave >> 2) * 112;
  const int wn = (wave & 3) * 64;
  const int mrow = lane & 15;
  const int quad = lane >> 4;
  const int kxor = mrow & 7;
  const int kx0 = (quad ^ kxor) * 8;      // B k-sub 0 slot (ushorts)
  const int kx1 = ((4 + quad) ^ kxor) * 8;

  int agb[7];                             // A granule base: quad-region + pixel
#pragma unroll
  for (int i = 0; i < 7; ++i) {
    int m = wm + i * 16 + mrow;           // 0..223
    int lh = m / 56;
    int w = m - lh * 56;
    agb[i] = quad * REGG + lh * 58 + w;
  }
  int bbase[4];
#pragma unroll
  for (int j = 0; j < 4; ++j) bbase[j] = (wn + j * 16 + mrow) * 64;

  floatx4 acc[7][4] = {};

  // ---- prologue: stage entire A footprint (11 uniform rounds per wave)
#pragma unroll
  for (int r = 0; r < 11; ++r) {
    int G = r * 512 + t;                  // 0..5631
    int gi = G / REGG;                    // region 0..15
    int q = G - gi * REGG;
    if (q >= 6 * 58) q = 0;               // pad lanes reload a valid granule
    const unsigned short* src =
        xt + ((size_t)(gi * BDIM + b) * (HP * WP) + hp0 * WP + q) * 8;
    __builtin_amdgcn_global_load_lds(
        (const __attribute__((address_space(1))) unsigned int*)src,
        (__attribute__((address_space(3))) unsigned int*)(ldsA + G * 8),
        16, 0, 0);
  }

  auto stageB = [&](int kt) {             // 4 loads/thread into buf kt&1
    const int khw = kt >> 1, ch = kt & 1;
    const int koff = khw * (C_OUTQ * C_INQ) + ch * 64;
    unsigned short* base = ldsB + (kt & 1) * 16384;
#pragma unroll
    for (int r = 0; r < 4; ++r)
      __builtin_amdgcn_global_load_lds(
          (const __attribute__((address_space(1))) unsigned int*)(wt + gbaseB[r] + koff),
          (__attribute__((address_space(3))) unsigned int*)(base + r * 4096 + t * 8),
          16, 0, 0);
  };

  stageB(0);
  stageB(1);                              // outstanding: 11 A + 4 B0 + 4 B1

#define BC8(p) __builtin_bit_cast(bf16x8, *(const ushort8*)(p))

  auto compute = [&](int kt) {
    const int khw = kt >> 1, ch = kt & 1;
    const int kh = khw / 3, kw = khw - kh * 3;
    const int kadd0 = ch * (8 * REGG) + kh * 58 + kw;   // + u*4*REGG for k-sub
    const unsigned short* Bb = ldsB + (kt & 1) * 16384;
    bf16x8 bfr[4][2];
#pragma unroll
    for (int j = 0; j < 4; ++j) {
      bfr[j][0] = BC8(Bb + bbase[j] + kx0);
      bfr[j][1] = BC8(Bb + bbase[j] + kx1);
    }
    __builtin_amdgcn_s_setprio(1);
#pragma unroll
    for (int i = 0; i < 7; ++i) {
      bf16x8 a0 = BC8(ldsA + (agb[i] + kadd0) * 8);
      bf16x8 a1 = BC8(ldsA + (agb[i] + kadd0 + 4 * REGG) * 8);
#pragma unroll
      for (int j = 0; j < 4; ++j)
        acc[i][j] = __builtin_amdgcn_mfma_f32_16x16x32_bf16(a0, bfr[j][0], acc[i][j], 0, 0, 0);
#pragma unroll
      for (int j = 0; j < 4; ++j)
        acc[i][j] = __builtin_amdgcn_mfma_f32_16x16x32_bf16(a1, bfr[j][1], acc[i][j], 0, 0, 0);
    }
    __builtin_amdgcn_s_setprio(0);
  };

  // K_STEP: counted wait (B(kt) landed; B(kt+1) stays in flight), barrier
  // (all waves' portions valid), compute, barrier (reads done), restage.
#define K_STEP(KT, VM, DOSTAGE)                                      \
  {                                                                  \
    asm volatile("s_waitcnt vmcnt(" VM ")" ::: "memory");            \
    __builtin_amdgcn_s_barrier();                                    \
    compute(KT);                                                     \
    __builtin_amdgcn_s_barrier();                                    \
    if (DOSTAGE) stageB((KT) + 2);                                   \
  }

#pragma unroll 1
  for (int tt = 0; tt < 16; tt += 2) {    // kt 0..15, staging B2..B17
    K_STEP(tt, "4", true);
    K_STEP(tt + 1, "4", true);
  }
  K_STEP(16, "4", false);                 // B17 stays in flight
  K_STEP(17, "0", false);                 // drain
#undef K_STEP
#undef BC8

  // epilogue: C/D layout col(n) = lane&15, row(m) = quad*4 + reg.
  // 4 consecutive pixels per lane -> one float4 store.
  float bv[4];
#pragma unroll
  for (int j = 0; j < 4; ++j) bv[j] = bias[wn + j * 16 + mrow];
  float* ob = out + (size_t)b * (C_OUTQ * HWPIX) + ht * 224;
#pragma unroll
  for (int i = 0; i < 7; ++i) {
    const int mloc = wm + i * 16 + quad * 4;
#pragma unroll
    for (int j = 0; j < 4; ++j) {
      const int n = wn + j * 16 + mrow;
      floatx4 v = acc[i][j];
      v[0] += bv[j]; v[1] += bv[j]; v[2] += bv[j]; v[3] += bv[j];
      *(floatx4*)(ob + (size_t)n * HWPIX + mloc) = v;
    }
  }
}

extern "C" void kernel_launch(void* const* d_in, const int* in_sizes, int n_in,
                              void* d_out, int out_size, void* d_ws, size_t ws_size,
                              hipStream_t stream) {
  const float* x    = (const float*)d_in[0];
  const float* w    = (const float*)d_in[1];
  const float* bias = (const float*)d_in[2];
  float* out = (float*)d_out;

  unsigned short* xt = (unsigned short*)d_ws;
  unsigned short* wt = (unsigned short*)((char*)d_ws + XT_BYTES);  // +589,824 B

  hipLaunchKernelGGL(prep_kernel, dim3(PAD_BLOCKS + 144), dim3(256), 0, stream,
                     x, xt, w, wt);
  hipLaunchKernelGGL(conv_gemm_kernel, dim3(448), dim3(512), 0, stream,
                     xt, wt, bias, out);
}